// Round 6
// baseline (61.305 us; speedup 1.0000x reference)
//
#include <hip/hip_runtime.h>

#define NROWS  32768
#define DDIM   256
#define KCODES 1024

typedef _Float16 half8 __attribute__((ext_vector_type(8)));
typedef float floatx4 __attribute__((ext_vector_type(4)));

// ws layout: [0,4096) f32 cnorm[1024];
//            [4096, 4096+524288) fp16 E' chunk-major fragment-ready:
//   16B slot = (ct*8 + kc)*1024 + lq*256 + cr   holds fp16 of
//   cb[ct*256+cr][kc*32 + lq*8 .. +8)

// ---------------------------------------------------------------------------
// prep kernel: codebook f32 -> fp16 fragment layout + np-pairwise cnorm
// (validated R1-R5, unchanged)
// ---------------------------------------------------------------------------
__global__ void prep_kernel(const float* __restrict__ cb,
                            float* __restrict__ cnorm,
                            _Float16* __restrict__ ep) {
    int idx  = blockIdx.x * 512 + threadIdx.x;   // 64 x 512 = 32768
    int code = idx >> 5, kl = idx & 31;
    int dc = kl >> 2, lq = kl & 3;
    int ct = code >> 8, cr = code & 255;
    const float4* s = reinterpret_cast<const float4*>(cb + (size_t)code * DDIM + kl * 8);
    float4 a = s[0], b = s[1];
    half8 h;
    h[0] = (_Float16)a.x; h[1] = (_Float16)a.y; h[2] = (_Float16)a.z; h[3] = (_Float16)a.w;
    h[4] = (_Float16)b.x; h[5] = (_Float16)b.y; h[6] = (_Float16)b.z; h[7] = (_Float16)b.w;
    size_t slot = (size_t)(ct * 8 + dc) * 1024 + lq * 256 + cr;
    *reinterpret_cast<half8*>(ep + slot * 8) = h;

    if (threadIdx.x < 16) {
        int k = blockIdx.x * 16 + threadIdx.x;
        const float* p = cb + (size_t)k * DDIM;
        float halves[2];
        for (int hh = 0; hh < 2; ++hh) {
            const float* aa = p + hh * 128;
            float r[8];
#pragma unroll
            for (int j = 0; j < 8; ++j) r[j] = __fmul_rn(aa[j], aa[j]);
            for (int i = 8; i < 128; i += 8) {
#pragma unroll
                for (int j = 0; j < 8; ++j)
                    r[j] = __fadd_rn(r[j], __fmul_rn(aa[i + j], aa[i + j]));
            }
            halves[hh] = __fadd_rn(__fadd_rn(__fadd_rn(r[0], r[1]), __fadd_rn(r[2], r[3])),
                                   __fadd_rn(__fadd_rn(r[4], r[5]), __fadd_rn(r[6], r[7])));
        }
        cnorm[k] = __fadd_rn(halves[0], halves[1]);
    }
}

// numpy-pairwise ||x||^2 from a global row pointer (validated R2-R5)
__device__ __forceinline__ float xnorm_np_g(const float* __restrict__ p) {
    float halves[2];
    for (int h = 0; h < 2; ++h) {
        const float* a = p + h * 128;
        float r[8];
#pragma unroll
        for (int j = 0; j < 8; ++j) r[j] = __fmul_rn(a[j], a[j]);
        for (int i = 8; i < 128; i += 8) {
#pragma unroll
            for (int j = 0; j < 8; ++j)
                r[j] = __fadd_rn(r[j], __fmul_rn(a[i + j], a[i + j]));
        }
        halves[h] = __fadd_rn(__fadd_rn(__fadd_rn(r[0], r[1]), __fadd_rn(r[2], r[3])),
                              __fadd_rn(__fadd_rn(r[4], r[5]), __fadd_rn(r[6], r[7])));
    }
    return __fadd_rn(halves[0], halves[1]);
}

// ---------------------------------------------------------------------------
// main kernel: 64 rows/block, 4 waves x 256-code strips. X panel in registers
// (128 VGPR/wave); E' streams L2->reg through a DEPTH-3 prefetch ring
// (12-16 loads in flight). Zero barriers/LDS in the main loop. s_setprio
// around each MFMA cluster. Top-2 + margin fast path + exact refine + gather
// (validated R2-R5, unchanged).
// ---------------------------------------------------------------------------
__global__ __launch_bounds__(256, 2) void som_mfma_kernel(
    const float* __restrict__ x, const float* __restrict__ cb,
    const float* __restrict__ cnorm, const _Float16* __restrict__ ep,
    float* __restrict__ out)
{
    __shared__ __align__(16) char smem[32768];

    const int tid  = threadIdx.x;
    const int lane = tid & 63, w = tid >> 6;     // wave 0..3 = code strip
    const int l15  = lane & 15, lq = lane >> 4;
    const int row0 = blockIdx.x * 64;

    // ---- stage X (64 rows) coalesced -> fp16 fragment layout in LDS ----
    {
        int row = tid >> 2, qd = tid & 3;
        const float4* src = reinterpret_cast<const float4*>(
            x + (size_t)(row0 + row) * DDIM + qd * 64);
        float4 f[16];
#pragma unroll
        for (int i = 0; i < 16; ++i) f[i] = src[i];
        half8* X16 = reinterpret_cast<half8*>(smem);
#pragma unroll
        for (int j = 0; j < 8; ++j) {
            float4 A = f[2 * j], B = f[2 * j + 1];
            half8 h;
            h[0] = (_Float16)A.x; h[1] = (_Float16)A.y; h[2] = (_Float16)A.z; h[3] = (_Float16)A.w;
            h[4] = (_Float16)B.x; h[5] = (_Float16)B.y; h[6] = (_Float16)B.z; h[7] = (_Float16)B.w;
            X16[(qd * 8 + j) * 64 + row] = h;   // [kq 0..31][row 0..63]
        }
    }
    __syncthreads();

    // ---- X panel -> registers: 4 row-frags x 8 k-chunks (128 VGPR) ----
    half8 xr0[8], xr1[8], xr2[8], xr3[8];
    {
        const half8* X16 = reinterpret_cast<const half8*>(smem);
#pragma unroll
        for (int kc = 0; kc < 8; ++kc) {
            int base = (kc * 4 + lq) * 64 + l15;
            xr0[kc] = X16[base];
            xr1[kc] = X16[base + 16];
            xr2[kc] = X16[base + 32];
            xr3[kc] = X16[base + 48];
        }
    }
    __syncthreads();   // X LDS dead from here

    const half8* epv = reinterpret_cast<const half8*>(ep);
    const int ebase = w * 8192 + lq * 256 + l15;    // 16B-slot units
    const int codebase = w * 256 + lq * 4;

    // half-frag index hIdx = cf*2 + h, 0..31.  E slot for (hIdx, j):
    //   epv[ebase + ((hIdx&1)*4 + j)*1024 + (hIdx>>1)*16]
    half8 eF[4][4];   // depth-3 prefetch ring, all indices static
#pragma unroll
    for (int pre = 0; pre < 3; ++pre) {
#pragma unroll
        for (int j = 0; j < 4; ++j)
            eF[pre][j] = epv[ebase + ((pre & 1) * 4 + j) * 1024 + (pre >> 1) * 16];
    }

    float t1[4], t2[4]; int i1[4], i2[4];
#pragma unroll
    for (int r = 0; r < 4; ++r) { t1[r] = -3.0e38f; t2[r] = -3.0e38f; i1[r] = 0; i2[r] = 0; }

#pragma unroll
    for (int cf = 0; cf < 16; ++cf) {
        floatx4 a0 = {0.f, 0.f, 0.f, 0.f}, a1 = a0, a2 = a0, a3 = a0;

#pragma unroll
        for (int h = 0; h < 2; ++h) {
            const int hIdx = cf * 2 + h;
            if (hIdx < 29) {   // issue loads for half-frag hIdx+3 (depth-3)
                const int f = hIdx + 3;
#pragma unroll
                for (int j = 0; j < 4; ++j)
                    eF[f & 3][j] = epv[ebase + ((f & 1) * 4 + j) * 1024 + (f >> 1) * 16];
            }
            __builtin_amdgcn_s_setprio(1);
#pragma unroll
            for (int j = 0; j < 4; ++j) {
                const int kc = h * 4 + j;
                half8 e = eF[hIdx & 3][j];
                a0 = __builtin_amdgcn_mfma_f32_16x16x32_f16(e, xr0[kc], a0, 0, 0, 0);
                a1 = __builtin_amdgcn_mfma_f32_16x16x32_f16(e, xr1[kc], a1, 0, 0, 0);
                a2 = __builtin_amdgcn_mfma_f32_16x16x32_f16(e, xr2[kc], a2, 0, 0, 0);
                a3 = __builtin_amdgcn_mfma_f32_16x16x32_f16(e, xr3[kc], a3, 0, 0, 0);
            }
            __builtin_amdgcn_s_setprio(0);
        }

        // ---- epilogue cf: q = dot - cnorm/2, per-lane top-2 per row-frag ----
        float4 cn = *reinterpret_cast<const float4*>(cnorm + w * 256 + cf * 16 + lq * 4);
        float cnl[4] = {cn.x, cn.y, cn.z, cn.w};
#pragma unroll
        for (int reg = 0; reg < 4; ++reg) {
            const int code = codebase + cf * 16 + reg;
#define TOP2(AV, RF) { float q = (AV) - 0.5f * cnl[reg];                        \
                       bool b1 = q > t1[RF], b2 = q > t2[RF];                   \
                       t2[RF] = b1 ? t1[RF] : (b2 ? q : t2[RF]);                \
                       i2[RF] = b1 ? i1[RF] : (b2 ? code : i2[RF]);             \
                       t1[RF] = b1 ? q : t1[RF];                                \
                       i1[RF] = b1 ? code : i1[RF]; }
            TOP2(a0[reg], 0)
            TOP2(a1[reg], 1)
            TOP2(a2[reg], 2)
            TOP2(a3[reg], 3)
#undef TOP2
        }
    }

    // ---- dump candidates: [64 rows][32 slots] (reuses X LDS) ----
    float* candV = reinterpret_cast<float*>(smem);           // 8 KB
    int*   candI = reinterpret_cast<int*>(smem + 8192);      // 8 KB
    int*   bmu   = reinterpret_cast<int*>(smem + 16384);
#pragma unroll
    for (int rf = 0; rf < 4; ++rf) {
        int r = rf * 16 + l15;
        int base = r * 32 + (w * 4 + lq) * 2;
        candV[base]     = t1[rf]; candI[base]     = i1[rf];
        candV[base + 1] = t2[rf]; candI[base + 1] = i2[rf];
    }
    __syncthreads();

    // ---- per-row decision: margin fast path or exact refine (validated) ----
    const float THR = 1.0e-2f;
    for (int p = 0; p < 8; ++p) {
        int r = p * 8 + w * 2 + (lane >> 5);
        int j = lane & 31;
        float v  = candV[r * 32 + j];
        int   id = candI[r * 32 + j];

        float V1 = v, V2 = -3.0e38f; int I1 = id, I2 = 0;
#pragma unroll
        for (int m = 1; m < 32; m <<= 1) {
            float pv1 = __shfl_xor(V1, m, 64); int pi1 = __shfl_xor(I1, m, 64);
            float pv2 = __shfl_xor(V2, m, 64); int pi2 = __shfl_xor(I2, m, 64);
            bool sw = pv1 > V1;
            float w1 = sw ? pv1 : V1; int wi1 = sw ? pi1 : I1;
            float lo = sw ? V1 : pv1; int loi = sw ? I1 : pi1;
            float s2 = sw ? pv2 : V2; int s2i = sw ? pi2 : I2;
            bool g = lo > s2;
            V1 = w1; I1 = wi1;
            V2 = g ? lo : s2; I2 = g ? loi : s2i;
        }

        int chosen;
        if (2.0f * (V1 - V2) >= THR) {
            chosen = I1;
        } else {
            const float* xr = x + (size_t)(row0 + r) * DDIM;
            const float* cr = cb + (size_t)id * DDIM;
            double m = 0.0;
            for (int d = 0; d < DDIM; ++d)
                m = fma((double)xr[d], (double)cr[d], m);
            float M  = (float)m;
            float xn = xnorm_np_g(xr);
            float s  = __fsub_rn(__fadd_rn(xn, cnorm[id]), __fmul_rn(2.0f, M));
#pragma unroll
            for (int m2 = 1; m2 < 32; m2 <<= 1) {
                float ps = __shfl_xor(s, m2, 64); int pid = __shfl_xor(id, m2, 64);
                bool take = (ps < s) || (ps == s && pid < id);
                s  = take ? ps  : s;
                id = take ? pid : id;
            }
            chosen = id;
        }
        if (j == 0) bmu[r] = chosen;
    }
    __syncthreads();

    // ---- gather: out[row] = codebook[bmu[row]] ----
    float4* out4 = reinterpret_cast<float4*>(out);
    const float4* cb4 = reinterpret_cast<const float4*>(cb);
#pragma unroll
    for (int p = 0; p < 16; ++p) {
        int idx = p * 256 + tid;
        int r = idx >> 6, sl = idx & 63;
        int code = bmu[r];
        out4[(size_t)(row0 + r) * 64 + sl] = cb4[(size_t)code * 64 + sl];
    }
}

extern "C" void kernel_launch(void* const* d_in, const int* in_sizes, int n_in,
                              void* d_out, int out_size, void* d_ws, size_t ws_size,
                              hipStream_t stream) {
    const float* x  = (const float*)d_in[0];
    const float* cb = (const float*)d_in[1];
    float* out = (float*)d_out;

    float*    cnorm = (float*)d_ws;
    _Float16* ep    = (_Float16*)((char*)d_ws + 4096);

    prep_kernel<<<dim3(64), dim3(512), 0, stream>>>(cb, cnorm, ep);
    som_mfma_kernel<<<dim3(512), dim3(256), 0, stream>>>(x, cb, cnorm, ep, out);
}